// Round 5
// baseline (73.006 us; speedup 1.0000x reference)
//
#include <hip/hip_runtime.h>
#include <float.h>

#define NUM_HEADS    32
#define NUM_KV_HEADS 8
#define HEAD_SIZE    128
#define Q_PER_KV     4
#define BLOCK_SZ     16
#define MAX_BLOCKS   128
#define SCALE        0.08838834764831845f

#define CHUNK_BLOCKS 8                            // cache blocks per chunk
#define CHUNK_TOK    (CHUNK_BLOCKS * BLOCK_SZ)    // 128 tokens
#define NCHUNK       (MAX_BLOCKS / CHUNK_BLOCKS)  // 16
#define WS_STRIDE    528   // 8 (m,l) + 512 (O), padded to 64B multiple

typedef float v4f __attribute__((ext_vector_type(4)));

// ---------------- kernel 1: per-chunk partial attention ----------------
// grid (NCHUNK, NUM_KV_HEADS, BATCH)  -- chunk index varies FASTEST.
// 64 threads (1 wave). launch_bounds(64,4) -> 128 VGPR budget, no spill.
__global__ __launch_bounds__(64, 4)
void paged_attn_chunk(const float* __restrict__ query,
                      const float* __restrict__ key_cache,
                      const float* __restrict__ value_cache,
                      const int* __restrict__ block_tables,
                      const int* __restrict__ context_lens,
                      float* __restrict__ ws) {
    const int c   = blockIdx.x;
    const int h   = blockIdx.y;
    const int b   = blockIdx.z;
    const int tid = threadIdx.x;  // 0..63

    const int ctx = context_lens[b];
    const int nb  = (ctx + BLOCK_SZ - 1) / BLOCK_SZ;
    const int b0  = c * CHUNK_BLOCKS;
    if (b0 >= nb) return;                     // inactive chunk; reducer skips
    const int nbl  = min(nb - b0, CHUNK_BLOCKS);
    const int last = ctx - 1;                 // stale cache slot -> masked here

    __shared__ float q_lds[Q_PER_KV * HEAD_SIZE];   // 2 KB, pre-scaled
    __shared__ float s_lds[Q_PER_KV * CHUNK_TOK];   // 2 KB scores -> probs

    // ---- stage Q (512 floats = 128 v4f), folding SCALE ----
    {
        const v4f* qg = reinterpret_cast<const v4f*>(
            query + ((size_t)b * NUM_HEADS + h * Q_PER_KV) * HEAD_SIZE);
        v4f* ql = reinterpret_cast<v4f*>(q_lds);
        ql[tid]      = qg[tid]      * SCALE;
        ql[tid + 64] = qg[tid + 64] * SCALE;
    }
    __syncthreads();

    // ---- scores: 4 lanes per block x 2 d-halves ----
    // lane bits: o = tid&3 (float4 token slice), bi8 = (tid>>2)&7 (block),
    //            rep = tid>>5 (d-half). Partner lane tid^32 has same (o,bi8).
    {
        const int o   = tid & 3;
        const int bi8 = (tid >> 2) & 7;
        const int rep = tid >> 5;
        v4f acc[Q_PER_KV];
        #pragma unroll
        for (int qh = 0; qh < Q_PER_KV; ++qh) acc[qh] = (v4f)0.f;

        if (bi8 < nbl) {
            const int phys = block_tables[b * MAX_BLOCKS + b0 + bi8];
            const v4f* kp = reinterpret_cast<const v4f*>(key_cache) +
                            ((size_t)phys * NUM_KV_HEADS + h) * (HEAD_SIZE * BLOCK_SZ / 4);
            const v4f* q4 = reinterpret_cast<const v4f*>(q_lds);
            #pragma unroll 4
            for (int d4 = rep * 16; d4 < rep * 16 + 16; ++d4) {
                v4f k[4];
                #pragma unroll
                for (int dd = 0; dd < 4; ++dd) k[dd] = kp[d4 * 16 + dd * 4 + o];
                #pragma unroll
                for (int qh = 0; qh < Q_PER_KV; ++qh) {
                    const v4f qv = q4[qh * (HEAD_SIZE / 4) + d4];
                    #pragma unroll
                    for (int dd = 0; dd < 4; ++dd) acc[qh] += qv[dd] * k[dd];
                }
            }
        }
        // merge the two d-halves (lane ^ 32)
        #pragma unroll
        for (int qh = 0; qh < Q_PER_KV; ++qh) {
            #pragma unroll
            for (int j = 0; j < 4; ++j)
                acc[qh][j] += __shfl_xor(acc[qh][j], 32);
        }
        if (rep == 0) {   // lanes 0..31 write all 128 token slots
            const int t0 = bi8 * BLOCK_SZ + o * 4;       // chunk-local token
            const int g0 = b0 * BLOCK_SZ + t0;           // global token
            #pragma unroll
            for (int qh = 0; qh < Q_PER_KV; ++qh) {
                v4f sv;
                #pragma unroll
                for (int j = 0; j < 4; ++j) {
                    const int g = g0 + j;
                    sv[j] = (bi8 < nbl && g < ctx && g != last) ? acc[qh][j] : -FLT_MAX;
                }
                *reinterpret_cast<v4f*>(&s_lds[qh * CHUNK_TOK + t0]) = sv;
            }
        }
    }
    __syncthreads();

    // ---- chunk-local softmax (un-normalized): 64 lanes x 2 tokens, qh seq ----
    float* wsp = ws + (((size_t)b * NUM_KV_HEADS + h) * NCHUNK + c) * WS_STRIDE;
    #pragma unroll
    for (int qh = 0; qh < Q_PER_KV; ++qh) {
        const float s0 = s_lds[qh * CHUNK_TOK + tid];
        const float s1 = s_lds[qh * CHUNK_TOK + tid + 64];
        float m = fmaxf(s0, s1);
        #pragma unroll
        for (int off = 32; off; off >>= 1) m = fmaxf(m, __shfl_xor(m, off));
        const float p0 = (s0 == -FLT_MAX) ? 0.f : __expf(s0 - m);
        const float p1 = (s1 == -FLT_MAX) ? 0.f : __expf(s1 - m);
        s_lds[qh * CHUNK_TOK + tid]      = p0;
        s_lds[qh * CHUNK_TOK + tid + 64] = p1;
        float l = p0 + p1;
        #pragma unroll
        for (int off = 32; off; off >>= 1) l += __shfl_xor(l, off);
        if (tid == 0) { wsp[qh] = m; wsp[Q_PER_KV + qh] = l; }
    }
    __syncthreads();

    // ---- partial PV: lane handles dims {tid, tid+64} over all chunk blocks ----
    {
        const int d0 = tid, d1 = tid + 64;
        float acc0[Q_PER_KV] = {0.f, 0.f, 0.f, 0.f};
        float acc1[Q_PER_KV] = {0.f, 0.f, 0.f, 0.f};
        for (int bil = 0; bil < nbl; ++bil) {
            const int phys = block_tables[b * MAX_BLOCKS + b0 + bil];
            const v4f* vp = reinterpret_cast<const v4f*>(value_cache) +
                            ((size_t)phys * NUM_KV_HEADS + h) * (HEAD_SIZE * BLOCK_SZ / 4);
            v4f vv0[4], vv1[4];
            #pragma unroll
            for (int j = 0; j < 4; ++j) { vv0[j] = vp[d0 * 4 + j]; vv1[j] = vp[d1 * 4 + j]; }
            #pragma unroll
            for (int qh = 0; qh < Q_PER_KV; ++qh) {
                const v4f* pq = reinterpret_cast<const v4f*>(
                    &s_lds[qh * CHUNK_TOK + bil * BLOCK_SZ]);
                #pragma unroll
                for (int j = 0; j < 4; ++j) {
                    const v4f p = pq[j];
                    acc0[qh] += p[0]*vv0[j][0] + p[1]*vv0[j][1] + p[2]*vv0[j][2] + p[3]*vv0[j][3];
                    acc1[qh] += p[0]*vv1[j][0] + p[1]*vv1[j][1] + p[2]*vv1[j][2] + p[3]*vv1[j][3];
                }
            }
        }
        float* wo = wsp + 2 * Q_PER_KV;
        #pragma unroll
        for (int qh = 0; qh < Q_PER_KV; ++qh) {
            wo[qh * HEAD_SIZE + d0] = acc0[qh];
            wo[qh * HEAD_SIZE + d1] = acc1[qh];
        }
    }
}

// ---------------- kernel 2: merge chunks + new token + normalize ----------------
// grid (NUM_KV_HEADS, BATCH), 512 threads.
__global__ __launch_bounds__(512, 2)
void paged_attn_reduce(const float* __restrict__ query,
                       const float* __restrict__ k_new,
                       const float* __restrict__ v_new,
                       const int* __restrict__ context_lens,
                       const float* __restrict__ ws,
                       float* __restrict__ out) {
    const int h   = blockIdx.x;
    const int b   = blockIdx.y;
    const int tid = threadIdx.x;

    __shared__ float snew_lds[Q_PER_KV];

    const int ctx = context_lens[b];
    const int nb  = (ctx + BLOCK_SZ - 1) / BLOCK_SZ;
    const int nch = (nb + CHUNK_BLOCKS - 1) / CHUNK_BLOCKS;

    // s_new[qh] = SCALE * q[qh] . k_new   (4 waves, one per qh)
    if (tid < 4 * 64) {
        const int w = tid >> 6, lane = tid & 63;
        const float* qp = query + ((size_t)b * NUM_HEADS + h * Q_PER_KV + w) * HEAD_SIZE;
        const float* kn = k_new + ((size_t)b * NUM_KV_HEADS + h) * HEAD_SIZE;
        float v = qp[lane] * kn[lane] + qp[lane + 64] * kn[lane + 64];
        #pragma unroll
        for (int off = 32; off; off >>= 1) v += __shfl_xor(v, off);
        if (lane == 0) snew_lds[w] = v * SCALE;
    }
    __syncthreads();

    const int qh = tid >> 7, d = tid & 127;
    const float* wsb = ws + ((size_t)b * NUM_KV_HEADS + h) * NCHUNK * WS_STRIDE;

    float M = -FLT_MAX, L = 0.f, acc = 0.f;
    for (int c = 0; c < nch; ++c) {
        const float* wsp = wsb + (size_t)c * WS_STRIDE;
        const float mc = wsp[qh];
        const float lc = wsp[Q_PER_KV + qh];
        const float oc = wsp[2 * Q_PER_KV + qh * HEAD_SIZE + d];
        const float nM = fmaxf(M, mc);
        const float eM = __expf(M - nM), ec = __expf(mc - nM);
        acc = acc * eM + oc * ec;
        L   = L   * eM + lc * ec;
        M   = nM;
    }
    // new token (exact, from k_new/v_new)
    {
        const float s  = snew_lds[qh];
        const float nM = fmaxf(M, s);
        const float eM = __expf(M - nM), es = __expf(s - nM);
        const float vn = v_new[((size_t)b * NUM_KV_HEADS + h) * HEAD_SIZE + d];
        acc = acc * eM + es * vn;
        L   = L   * eM + es;
    }
    out[((size_t)b * NUM_HEADS + h * Q_PER_KV + qh) * HEAD_SIZE + d] = acc / L;
}

extern "C" void kernel_launch(void* const* d_in, const int* in_sizes, int n_in,
                              void* d_out, int out_size, void* d_ws, size_t ws_size,
                              hipStream_t stream) {
    const float* query       = (const float*)d_in[0];
    const float* k_new       = (const float*)d_in[1];
    const float* v_new       = (const float*)d_in[2];
    const float* key_cache   = (const float*)d_in[3];
    const float* value_cache = (const float*)d_in[4];
    const int*   block_tables  = (const int*)d_in[5];
    const int*   context_lens  = (const int*)d_in[6];
    float* out = (float*)d_out;
    float* ws  = (float*)d_ws;

    const int batch = in_sizes[6];

    dim3 g1(NCHUNK, NUM_KV_HEADS, batch);   // chunk index fastest
    paged_attn_chunk<<<g1, 64, 0, stream>>>(query, key_cache, value_cache,
                                            block_tables, context_lens, ws);
    dim3 g2(NUM_KV_HEADS, batch);
    paged_attn_reduce<<<g2, 512, 0, stream>>>(query, k_new, v_new,
                                              context_lens, ws, out);
}